// Round 1
// baseline (343.393 us; speedup 1.0000x reference)
//
#include <hip/hip_runtime.h>
#include <hip/hip_bf16.h>
#include <hip/hip_fp16.h>

#define DEV __device__ __forceinline__

typedef __attribute__((ext_vector_type(8))) _Float16 h8;
typedef __attribute__((ext_vector_type(4))) float floatx4;

DEV float bf2f(unsigned short b) { return __uint_as_float(((unsigned)b) << 16); }

DEV void async_ld16(const void* g, void* l) {
  __builtin_amdgcn_global_load_lds(
      (const __attribute__((address_space(1))) unsigned int*)g,
      (__attribute__((address_space(3))) unsigned int*)l, 16, 0, 0);
}

// Runtime dtype probe (safety net): 1 if float tensors are bf16-packed, 0 if fp32.
DEV int detect_bf16(const void* x_mean) {
  const unsigned* w = (const unsigned*)x_mean;
  unsigned v = w[threadIdx.x & 63];
  unsigned ex = (v >> 7) & 0xFFu;
  int vote = (ex >= 100u && ex <= 144u) ? 1 : 0;
  unsigned long long b = __ballot(vote);
  return __popcll(b) >= 48 ? 1 : 0;
}

DEV float load_elem(const void* p, int isbf, size_t i) {
  return isbf ? bf2f(((const unsigned short*)p)[i]) : ((const float*)p)[i];
}

// Load 8 consecutive elements (fp32 or bf16), scale, -> 8 fp16 into LDS.
DEV void stage8h(const void* src, int isbf, size_t idx, float scale, _Float16* dst) {
  h8 o;
  if (isbf) {
    const unsigned short* s = (const unsigned short*)src + idx;
#pragma unroll
    for (int j = 0; j < 8; ++j) o[j] = (_Float16)(bf2f(s[j]) * scale);
  } else {
    const float* f = (const float*)src + idx;
    float4 a = *(const float4*)f;
    float4 b = *(const float4*)(f + 4);
    o[0] = (_Float16)(a.x * scale); o[1] = (_Float16)(a.y * scale);
    o[2] = (_Float16)(a.z * scale); o[3] = (_Float16)(a.w * scale);
    o[4] = (_Float16)(b.x * scale); o[5] = (_Float16)(b.y * scale);
    o[6] = (_Float16)(b.z * scale); o[7] = (_Float16)(b.w * scale);
  }
  *(h8*)dst = o;
}

// ---------- K1: four input projections, 128x128 tile, K=256 ----------
// Output fp16 fragment-linear via LDS-transpose epilogue (coalesced 16B stores).
struct ProjArgs {
  const void* A[4];
  const void* B[4];
  const void* bias[4];
  _Float16* C[4];
  int fl_tpc[4];
  float scale[4];
  int bias_row[4];
  const void* xdet;
};

__global__ __launch_bounds__(256) void proj_kernel(ProjArgs p) {
  __shared__ __align__(16) char smem[34816];  // k-loop: As+Bs 16 KB; epilogue: Ts 128x136
  _Float16* As = (_Float16*)smem;
  _Float16* Bs = As + 4096;
  _Float16* Ts = (_Float16*)smem;
  int isbf = detect_bf16(p.xdet);
  int z = blockIdx.z;
  size_t i0, j0;
  if (z < 2) { i0 = (size_t)blockIdx.x * 128; j0 = (size_t)blockIdx.y * 128; }
  else       { i0 = (size_t)blockIdx.y * 128; j0 = (size_t)blockIdx.x * 128; }
  const void* A = p.A[z];
  const void* B = p.B[z];
  const void* bias = p.bias[z];
  const float scale = p.scale[z];
  const int bias_row = p.bias_row[z];
  const int tpc = p.fl_tpc[z];
  _Float16* C = p.C[z];
  const int t = threadIdx.x;
  const int lane = t & 63, wave = t >> 6;
  const int wr = wave >> 1, wc = wave & 1;
  const int q = lane >> 4, m = lane & 15;
  floatx4 acc[4][4] = {};
  for (int k0 = 0; k0 < 256; k0 += 32) {
#pragma unroll
    for (int it = 0; it < 2; ++it) {
      int e = it * 2048 + t * 8;
      int row = e >> 5, col = e & 31;
      stage8h(A, isbf, (i0 + row) * (size_t)256 + k0 + col, 1.f, &As[e]);
      stage8h(B, isbf, (j0 + row) * (size_t)256 + k0 + col, 1.f, &Bs[e]);
    }
    __syncthreads();
    h8 af[4], bfr[4];
#pragma unroll
    for (int r = 0; r < 4; ++r)
      af[r] = *(const h8*)&As[(wr * 64 + r * 16 + m) * 32 + q * 8];
#pragma unroll
    for (int c = 0; c < 4; ++c)
      bfr[c] = *(const h8*)&Bs[(wc * 64 + c * 16 + m) * 32 + q * 8];
#pragma unroll
    for (int r = 0; r < 4; ++r)
#pragma unroll
      for (int c = 0; c < 4; ++c)
        acc[r][c] = __builtin_amdgcn_mfma_f32_16x16x32_f16(af[r], bfr[c], acc[r][c], 0, 0, 0);
    __syncthreads();
  }
  // bias + scale, into LDS transpose buffer
#pragma unroll
  for (int r = 0; r < 4; ++r)
#pragma unroll
    for (int c = 0; c < 4; ++c) {
      size_t col = j0 + wc * 64 + c * 16 + m;
      float bcol = bias_row ? 0.f : load_elem(bias, isbf, col);
#pragma unroll
      for (int g = 0; g < 4; ++g) {
        size_t row = i0 + wr * 64 + r * 16 + q * 4 + g;
        float val = acc[r][c][g] + bcol;
        if (bias_row) val += load_elem(bias, isbf, row);
        Ts[(wr * 64 + r * 16 + q * 4 + g) * 136 + wc * 64 + c * 16 + m] =
            (_Float16)(val * scale);
      }
    }
  __syncthreads();
  // coalesced fragment-linear writeout: 32 tiles, 16 B/lane
  size_t ti0 = i0 >> 4, tj0 = j0 >> 5;
#pragma unroll
  for (int it = 0; it < 8; ++it) {
    int cch = it * 4 + wave;
    int ci = cch >> 2, ck = cch & 3;
    int il = ci * 16 + (lane & 15);
    int jl = ck * 32 + (lane >> 4) * 8;
    h8 v = *(const h8*)&Ts[il * 136 + jl];
    *(h8*)&C[((ti0 + ci) * (size_t)tpc + (tj0 + ck)) * 512 + lane * 8] = v;
  }
}

// ---------- K2: E = exp(q'@k^T)*2^-6, fragment-linear out + row sums ----------
// R9: 2-phase double-buffered pipeline (T3 minimum form): stage tile t+1 before
// MFMA of tile t, single barrier per iteration. Both 16 KB buffers live inside
// the 34816 B block; Ts epilogue aliases them after the final barrier.
__global__ __launch_bounds__(256) void qk_exp_kernel(const _Float16* __restrict__ qb,
                                                     const _Float16* __restrict__ kb,
                                                     _Float16* __restrict__ E,
                                                     float* __restrict__ rs) {
  __shared__ __align__(16) char smem[34816];  // 2 x (As 8 KB + Bs 8 KB) = 32 KB; Ts 34816
  _Float16* base = (_Float16*)smem;
  _Float16* Ts = (_Float16*)smem;
  const int t = threadIdx.x;
  const int lane = t & 63, wave = t >> 6;
  const int wr = wave >> 1, wc = wave & 1;
  const int q = lane >> 4, m = lane & 15;
  const size_t bx = blockIdx.x, by = blockIdx.y;
  const size_t i0 = bx * 128;
  floatx4 acc[4][4] = {};

  auto stage = [&](int buf, int kt) {
    _Float16* A = base + buf * 8192;
    _Float16* B = A + 4096;
#pragma unroll
    for (int it = 0; it < 2; ++it) {
      int c = it * 4 + wave;
      async_ld16(&qb[((bx * 8 + c) * 8 + kt) * 512 + lane * 8], &A[c * 512 + lane * 8]);
      async_ld16(&kb[((by * 8 + c) * 8 + kt) * 512 + lane * 8], &B[c * 512 + lane * 8]);
    }
  };

  stage(0, 0);
  __syncthreads();  // compiler drains vmcnt(0) before barrier: buf0 ready
  int cur = 0;
  for (int kt = 0; kt < 8; ++kt) {
    if (kt < 7) stage(cur ^ 1, kt + 1);  // in flight across the MFMA phase
    _Float16* As = base + cur * 8192;
    _Float16* Bs = As + 4096;
    h8 af[4], bfr[4];
#pragma unroll
    for (int r = 0; r < 4; ++r)
      af[r] = *(const h8*)&As[(wr * 4 + r) * 512 + lane * 8];
#pragma unroll
    for (int c = 0; c < 4; ++c)
      bfr[c] = *(const h8*)&Bs[(wc * 4 + c) * 512 + lane * 8];
#pragma unroll
    for (int r = 0; r < 4; ++r)
#pragma unroll
      for (int c = 0; c < 4; ++c)
        acc[r][c] = __builtin_amdgcn_mfma_f32_16x16x32_f16(af[r], bfr[c], acc[r][c], 0, 0, 0);
    __syncthreads();  // next buffer's loads drained here, prev reads all done
    cur ^= 1;
  }
#pragma unroll
  for (int r = 0; r < 4; ++r)
#pragma unroll
    for (int c = 0; c < 4; ++c)
#pragma unroll
      for (int g = 0; g < 4; ++g)
        acc[r][c][g] = __expf(fminf(acc[r][c][g], 8.f)) * 0.015625f;
#pragma unroll
  for (int r = 0; r < 4; ++r)
#pragma unroll
    for (int g = 0; g < 4; ++g) {
      float part = acc[r][0][g] + acc[r][1][g] + acc[r][2][g] + acc[r][3][g];
      part += __shfl_xor(part, 1);
      part += __shfl_xor(part, 2);
      part += __shfl_xor(part, 4);
      part += __shfl_xor(part, 8);
      if (m == 0)
        unsafeAtomicAdd(&rs[i0 + wr * 64 + r * 16 + q * 4 + g], part);
    }
#pragma unroll
  for (int r = 0; r < 4; ++r)
#pragma unroll
    for (int c = 0; c < 4; ++c)
#pragma unroll
      for (int g = 0; g < 4; ++g)
        Ts[(wr * 64 + r * 16 + q * 4 + g) * 136 + wc * 64 + c * 16 + m] =
            (_Float16)acc[r][c][g];
  __syncthreads();
#pragma unroll
  for (int it = 0; it < 8; ++it) {
    int cch = it * 4 + wave;
    int ci = cch >> 2, ck = cch & 3;
    int il = ci * 16 + (lane & 15);
    int jl = ck * 32 + (lane >> 4) * 8;
    h8 v = *(const h8*)&Ts[il * 136 + jl];
    *(h8*)&E[((bx * 8 + ci) * 256 + by * 4 + ck) * 512 + lane * 8] = v;
  }
}

// ---------- zero helpers ----------
__global__ __launch_bounds__(256) void zero_rs_kernel(float* __restrict__ rs) {
  rs[blockIdx.x * 256 + threadIdx.x] = 0.f;
}
__global__ __launch_bounds__(256) void zero_acc_kernel(float* __restrict__ a,
                                                       float* __restrict__ b) {
  size_t i = ((size_t)blockIdx.x * 256 + threadIdx.x) * 4;
  float4 z = {0.f, 0.f, 0.f, 0.f};
  *(float4*)(a + i) = z;
  *(float4*)(b + i) = z;
}

// ---------- K4: fused split-K  otm += (E@v^T)/rs, otv += (E^2@v_var^T)/rs^2 ----------
// R9: 2-phase double-buffered pipeline. LDS 20 KB -> 40 KB (still 4 blocks/CU).
// Prefetch k-tile t+1's global_load_lds before MFMA of tile t; one barrier/iter.
__global__ __launch_bounds__(256, 4) void av_fused(const _Float16* __restrict__ E,
                                                   const _Float16* __restrict__ vT,
                                                   const _Float16* __restrict__ vvT,
                                                   const float* __restrict__ rs,
                                                   float* __restrict__ otm,
                                                   float* __restrict__ otv) {
  __shared__ __align__(16) _Float16 As[2][4 * 512];    // 8 KB
  __shared__ __align__(16) _Float16 B1s[2][8 * 512];   // 16 KB
  __shared__ __align__(16) _Float16 B2s[2][8 * 512];   // 16 KB
  const int t = threadIdx.x;
  const int lane = t & 63, wave = t >> 6;
  const int wr = wave >> 1, wc = wave & 1;
  const int q = lane >> 4, m = lane & 15;
  const size_t bx = blockIdx.x, by = blockIdx.y;
  const int kt0 = (blockIdx.z == 0) ? 0 : 86 + (blockIdx.z - 1) * 85;
  const int ktn = (blockIdx.z == 0) ? 86 : 85;
  // hoisted staging offsets (elements), +512 per k-tile via kk*512
  const size_t aoff = ((bx * 4 + (size_t)wave) * 256 + (size_t)kt0) * 512 + lane * 8;
  const size_t boff0 = ((by * 8 + (size_t)wave) * 256 + (size_t)kt0) * 512 + lane * 8;
  const size_t boff1 = ((by * 8 + (size_t)wave + 4) * 256 + (size_t)kt0) * 512 + lane * 8;

  auto stage = [&](int buf, int kk) {
    size_t o = (size_t)kk * 512;
    async_ld16(&E[aoff + o], &As[buf][wave * 512 + lane * 8]);
    async_ld16(&vT[boff0 + o], &B1s[buf][wave * 512 + lane * 8]);
    async_ld16(&vT[boff1 + o], &B1s[buf][(wave + 4) * 512 + lane * 8]);
    async_ld16(&vvT[boff0 + o], &B2s[buf][wave * 512 + lane * 8]);
    async_ld16(&vvT[boff1 + o], &B2s[buf][(wave + 4) * 512 + lane * 8]);
  };

  floatx4 accm[2][4] = {}, accv[2][4] = {};
  stage(0, 0);
  __syncthreads();  // vmcnt(0) drained by compiler before barrier: buf0 ready
  int cur = 0;
  for (int kk = 0; kk < ktn; ++kk) {
    if (kk + 1 < ktn) stage(cur ^ 1, kk + 1);  // loads fly during ds_read+MFMA
    h8 a[2], a2[2], b1[4], b2[4];
#pragma unroll
    for (int r = 0; r < 2; ++r) {
      a[r] = *(const h8*)&As[cur][(wr * 2 + r) * 512 + lane * 8];
      a2[r] = a[r] * a[r];  // v_pk_mul_f16
    }
#pragma unroll
    for (int c = 0; c < 4; ++c) {
      b1[c] = *(const h8*)&B1s[cur][(wc * 4 + c) * 512 + lane * 8];
      b2[c] = *(const h8*)&B2s[cur][(wc * 4 + c) * 512 + lane * 8];
    }
#pragma unroll
    for (int r = 0; r < 2; ++r)
#pragma unroll
      for (int c = 0; c < 4; ++c) {
        accm[r][c] = __builtin_amdgcn_mfma_f32_16x16x32_f16(a[r], b1[c], accm[r][c], 0, 0, 0);
        accv[r][c] = __builtin_amdgcn_mfma_f32_16x16x32_f16(a2[r], b2[c], accv[r][c], 0, 0, 0);
      }
    __syncthreads();  // next buffer's loads complete; prev buffer's reads all done
    cur ^= 1;
  }
  // epilogue: normalize by rs (commutes with split-K sum), atomic accumulate
#pragma unroll
  for (int r = 0; r < 2; ++r)
#pragma unroll
    for (int g = 0; g < 4; ++g) {
      size_t row = bx * 64 + wr * 32 + r * 16 + q * 4 + g;
      float inv = 1.f / rs[row];
      float inv2 = inv * inv;
#pragma unroll
      for (int c = 0; c < 4; ++c) {
        size_t col = by * 128 + wc * 64 + c * 16 + m;
        unsafeAtomicAdd(&otm[row * 256 + col], accm[r][c][g] * inv);
        unsafeAtomicAdd(&otv[row * 256 + col], accv[r][c][g] * inv2);
      }
    }
}

// ---------- K5: out_mean(fp32) = otm @ Wo^T + bo.  BM=64, BN=128, grid (128,2) ----------
__global__ __launch_bounds__(256) void final_kernel(const float* __restrict__ ot,
                                                    const void* Wo, const void* bo,
                                                    const void* xdet,
                                                    float* __restrict__ Cm) {
  __shared__ __align__(16) _Float16 As[64 * 32];    // 4 KB
  __shared__ __align__(16) _Float16 Bs[128 * 32];   // 8 KB
  int isbf = detect_bf16(xdet);
  const int t = threadIdx.x;
  const int lane = t & 63, wave = t >> 6;
  const int wr = wave >> 1, wc = wave & 1;
  const int q = lane >> 4, m = lane & 15;
  const size_t i0 = (size_t)blockIdx.x * 64, j0 = (size_t)blockIdx.y * 128;
  floatx4 acc[2][4] = {};
  for (int k0 = 0; k0 < 256; k0 += 32) {
    {
      int e = t * 8;
      int row = e >> 5, col = e & 31;
      stage8h(ot, 0, (i0 + row) * (size_t)256 + k0 + col, 1.f, &As[e]);
    }
#pragma unroll
    for (int it = 0; it < 2; ++it) {
      int e = it * 2048 + t * 8;
      int row = e >> 5, col = e & 31;
      stage8h(Wo, isbf, (j0 + row) * (size_t)256 + k0 + col, 1.f, &Bs[e]);
    }
    __syncthreads();
    h8 af[2], bfr[4];
#pragma unroll
    for (int r = 0; r < 2; ++r)
      af[r] = *(const h8*)&As[(wr * 32 + r * 16 + m) * 32 + q * 8];
#pragma unroll
    for (int c = 0; c < 4; ++c)
      bfr[c] = *(const h8*)&Bs[(wc * 64 + c * 16 + m) * 32 + q * 8];
#pragma unroll
    for (int r = 0; r < 2; ++r)
#pragma unroll
      for (int c = 0; c < 4; ++c)
        acc[r][c] = __builtin_amdgcn_mfma_f32_16x16x32_f16(af[r], bfr[c], acc[r][c], 0, 0, 0);
    __syncthreads();
  }
#pragma unroll
  for (int r = 0; r < 2; ++r)
#pragma unroll
    for (int c = 0; c < 4; ++c) {
      size_t col = j0 + wc * 64 + c * 16 + m;
      float bcol = load_elem(bo, isbf, col);
#pragma unroll
      for (int g = 0; g < 4; ++g) {
        size_t row = i0 + wr * 32 + r * 16 + q * 4 + g;
        Cm[row * 256 + col] = acc[r][c][g] + bcol;
      }
    }
}

extern "C" void kernel_launch(void* const* d_in, const int* in_sizes, int n_in,
                              void* d_out, int out_size, void* d_ws, size_t ws_size,
                              hipStream_t stream) {
  const void* x_mean = d_in[0];
  const void* x_var  = d_in[1];
  // d_in[2] edge_index, d_in[3] edge_timestamps: unused by the reference
  const void* Wq   = d_in[4];
  const void* bq   = d_in[5];
  const void* Wk   = d_in[6];
  const void* bk   = d_in[7];
  const void* Wv   = d_in[8];
  const void* bv   = d_in[9];
  const void* Wo   = d_in[10];
  const void* bo   = d_in[11];
  const void* Wvar = d_in[12];
  const void* bvar = d_in[13];
  float* out = (float*)d_out;  // [out_mean (8192*256) | out_var (8192*256)] fp32

  const size_t NE_S = 67108864;  // 8192*8192
  const size_t NE_P = 2097152;   // 8192*256
  if (ws_size < (NE_S + 5 * NE_P) * 2) return;  // ~155 MB scratch
  _Float16* w   = (_Float16*)d_ws;
  _Float16* S   = w;              // E = exp(logits)*2^-6, fragment-linear [8192x8192]
  _Float16* qb  = w + NE_S;       // q*0.125 (+bq), fragment-linear [8192x256]
  _Float16* kb  = qb + NE_P;      // k, fragment-linear [8192x256]
  _Float16* vT  = kb + NE_P;      // v^T, fragment-linear [256x8192]
  _Float16* vvT = vT + NE_P;      // v_var^T, fragment-linear [256x8192]
  float* rs     = (float*)(vvT + NE_P);  // row sums of E, fp32 [8192]
  // fp32 mean accumulator aliases qb+kb (dead after qk_exp): 8 MB exactly
  float* ot_f32 = (float*)qb;

  ProjArgs p;
  p.A[0] = x_mean; p.B[0] = Wq;     p.bias[0] = bq;   p.C[0] = qb;  p.fl_tpc[0] = 8;   p.scale[0] = 0.125f; p.bias_row[0] = 0;
  p.A[1] = x_mean; p.B[1] = Wk;     p.bias[1] = bk;   p.C[1] = kb;  p.fl_tpc[1] = 8;   p.scale[1] = 1.f;    p.bias_row[1] = 0;
  p.A[2] = Wv;     p.B[2] = x_mean; p.bias[2] = bv;   p.C[2] = vT;  p.fl_tpc[2] = 256; p.scale[2] = 1.f;    p.bias_row[2] = 1;
  p.A[3] = Wvar;   p.B[3] = x_var;  p.bias[3] = bvar; p.C[3] = vvT; p.fl_tpc[3] = 256; p.scale[3] = 1.f;    p.bias_row[3] = 1;
  p.xdet = x_mean;

  zero_rs_kernel<<<dim3(32), 256, 0, stream>>>(rs);
  proj_kernel<<<dim3(64, 2, 4), 256, 0, stream>>>(p);
  qk_exp_kernel<<<dim3(64, 64), 256, 0, stream>>>(qb, kb, S, rs);
  // zero AFTER qk_exp (ot_f32 overwrites qb/kb), BEFORE av
  zero_acc_kernel<<<dim3(2048), 256, 0, stream>>>(ot_f32, out + NE_P);
  av_fused<<<dim3(128, 2, 3), 256, 0, stream>>>(S, vT, vvT, rs, ot_f32, out + NE_P);
  final_kernel<<<dim3(128, 2), 256, 0, stream>>>(ot_f32, Wo, bo, x_mean, out);
}

// Round 2
// 325.422 us; speedup vs baseline: 1.0552x; 1.0552x over previous
//
#include <hip/hip_runtime.h>
#include <hip/hip_bf16.h>
#include <hip/hip_fp16.h>

#define DEV __device__ __forceinline__

typedef __attribute__((ext_vector_type(8))) _Float16 h8;
typedef __attribute__((ext_vector_type(4))) float floatx4;

DEV float bf2f(unsigned short b) { return __uint_as_float(((unsigned)b) << 16); }

DEV void async_ld16(const void* g, void* l) {
  __builtin_amdgcn_global_load_lds(
      (const __attribute__((address_space(1))) unsigned int*)g,
      (__attribute__((address_space(3))) unsigned int*)l, 16, 0, 0);
}

// Runtime dtype probe (safety net): 1 if float tensors are bf16-packed, 0 if fp32.
DEV int detect_bf16(const void* x_mean) {
  const unsigned* w = (const unsigned*)x_mean;
  unsigned v = w[threadIdx.x & 63];
  unsigned ex = (v >> 7) & 0xFFu;
  int vote = (ex >= 100u && ex <= 144u) ? 1 : 0;
  unsigned long long b = __ballot(vote);
  return __popcll(b) >= 48 ? 1 : 0;
}

DEV float load_elem(const void* p, int isbf, size_t i) {
  return isbf ? bf2f(((const unsigned short*)p)[i]) : ((const float*)p)[i];
}

// Load 8 consecutive elements (fp32 or bf16), scale, -> 8 fp16 into LDS.
DEV void stage8h(const void* src, int isbf, size_t idx, float scale, _Float16* dst) {
  h8 o;
  if (isbf) {
    const unsigned short* s = (const unsigned short*)src + idx;
#pragma unroll
    for (int j = 0; j < 8; ++j) o[j] = (_Float16)(bf2f(s[j]) * scale);
  } else {
    const float* f = (const float*)src + idx;
    float4 a = *(const float4*)f;
    float4 b = *(const float4*)(f + 4);
    o[0] = (_Float16)(a.x * scale); o[1] = (_Float16)(a.y * scale);
    o[2] = (_Float16)(a.z * scale); o[3] = (_Float16)(a.w * scale);
    o[4] = (_Float16)(b.x * scale); o[5] = (_Float16)(b.y * scale);
    o[6] = (_Float16)(b.z * scale); o[7] = (_Float16)(b.w * scale);
  }
  *(h8*)dst = o;
}

// ---------- K1: four input projections, 128x128 tile, K=256 ----------
// Output fp16 fragment-linear via LDS-transpose epilogue (coalesced 16B stores).
struct ProjArgs {
  const void* A[4];
  const void* B[4];
  const void* bias[4];
  _Float16* C[4];
  int fl_tpc[4];
  float scale[4];
  int bias_row[4];
  const void* xdet;
};

__global__ __launch_bounds__(256) void proj_kernel(ProjArgs p) {
  __shared__ __align__(16) char smem[34816];  // k-loop: As+Bs 16 KB; epilogue: Ts 128x136
  _Float16* As = (_Float16*)smem;
  _Float16* Bs = As + 4096;
  _Float16* Ts = (_Float16*)smem;
  int isbf = detect_bf16(p.xdet);
  int z = blockIdx.z;
  size_t i0, j0;
  if (z < 2) { i0 = (size_t)blockIdx.x * 128; j0 = (size_t)blockIdx.y * 128; }
  else       { i0 = (size_t)blockIdx.y * 128; j0 = (size_t)blockIdx.x * 128; }
  const void* A = p.A[z];
  const void* B = p.B[z];
  const void* bias = p.bias[z];
  const float scale = p.scale[z];
  const int bias_row = p.bias_row[z];
  const int tpc = p.fl_tpc[z];
  _Float16* C = p.C[z];
  const int t = threadIdx.x;
  const int lane = t & 63, wave = t >> 6;
  const int wr = wave >> 1, wc = wave & 1;
  const int q = lane >> 4, m = lane & 15;
  floatx4 acc[4][4] = {};
  for (int k0 = 0; k0 < 256; k0 += 32) {
#pragma unroll
    for (int it = 0; it < 2; ++it) {
      int e = it * 2048 + t * 8;
      int row = e >> 5, col = e & 31;
      stage8h(A, isbf, (i0 + row) * (size_t)256 + k0 + col, 1.f, &As[e]);
      stage8h(B, isbf, (j0 + row) * (size_t)256 + k0 + col, 1.f, &Bs[e]);
    }
    __syncthreads();
    h8 af[4], bfr[4];
#pragma unroll
    for (int r = 0; r < 4; ++r)
      af[r] = *(const h8*)&As[(wr * 64 + r * 16 + m) * 32 + q * 8];
#pragma unroll
    for (int c = 0; c < 4; ++c)
      bfr[c] = *(const h8*)&Bs[(wc * 64 + c * 16 + m) * 32 + q * 8];
#pragma unroll
    for (int r = 0; r < 4; ++r)
#pragma unroll
      for (int c = 0; c < 4; ++c)
        acc[r][c] = __builtin_amdgcn_mfma_f32_16x16x32_f16(af[r], bfr[c], acc[r][c], 0, 0, 0);
    __syncthreads();
  }
  // bias + scale, into LDS transpose buffer
#pragma unroll
  for (int r = 0; r < 4; ++r)
#pragma unroll
    for (int c = 0; c < 4; ++c) {
      size_t col = j0 + wc * 64 + c * 16 + m;
      float bcol = bias_row ? 0.f : load_elem(bias, isbf, col);
#pragma unroll
      for (int g = 0; g < 4; ++g) {
        size_t row = i0 + wr * 64 + r * 16 + q * 4 + g;
        float val = acc[r][c][g] + bcol;
        if (bias_row) val += load_elem(bias, isbf, row);
        Ts[(wr * 64 + r * 16 + q * 4 + g) * 136 + wc * 64 + c * 16 + m] =
            (_Float16)(val * scale);
      }
    }
  __syncthreads();
  // coalesced fragment-linear writeout: 32 tiles, 16 B/lane
  size_t ti0 = i0 >> 4, tj0 = j0 >> 5;
#pragma unroll
  for (int it = 0; it < 8; ++it) {
    int cch = it * 4 + wave;
    int ci = cch >> 2, ck = cch & 3;
    int il = ci * 16 + (lane & 15);
    int jl = ck * 32 + (lane >> 4) * 8;
    h8 v = *(const h8*)&Ts[il * 136 + jl];
    *(h8*)&C[((ti0 + ci) * (size_t)tpc + (tj0 + ck)) * 512 + lane * 8] = v;
  }
}

// ---------- K2: E = exp(q'@k^T)*2^-6, fragment-linear out + row sums ----------
// (proven R8 version, reverted: 91 us)
__global__ __launch_bounds__(256) void qk_exp_kernel(const _Float16* __restrict__ qb,
                                                     const _Float16* __restrict__ kb,
                                                     _Float16* __restrict__ E,
                                                     float* __restrict__ rs) {
  __shared__ __align__(16) char smem[128 * 136 * 2];  // 34816 B
  _Float16* As = (_Float16*)smem;
  _Float16* Bs = As + 4096;
  _Float16* Ts = (_Float16*)smem;
  const int t = threadIdx.x;
  const int lane = t & 63, wave = t >> 6;
  const int wr = wave >> 1, wc = wave & 1;
  const int q = lane >> 4, m = lane & 15;
  const size_t bx = blockIdx.x, by = blockIdx.y;
  const size_t i0 = bx * 128;
  floatx4 acc[4][4] = {};
  for (int kt = 0; kt < 8; ++kt) {
#pragma unroll
    for (int it = 0; it < 2; ++it) {
      int c = it * 4 + wave;
      async_ld16(&qb[((bx * 8 + c) * 8 + kt) * 512 + lane * 8], &As[c * 512 + lane * 8]);
      async_ld16(&kb[((by * 8 + c) * 8 + kt) * 512 + lane * 8], &Bs[c * 512 + lane * 8]);
    }
    __syncthreads();
    h8 af[4], bfr[4];
#pragma unroll
    for (int r = 0; r < 4; ++r)
      af[r] = *(const h8*)&As[(wr * 4 + r) * 512 + lane * 8];
#pragma unroll
    for (int c = 0; c < 4; ++c)
      bfr[c] = *(const h8*)&Bs[(wc * 4 + c) * 512 + lane * 8];
#pragma unroll
    for (int r = 0; r < 4; ++r)
#pragma unroll
      for (int c = 0; c < 4; ++c)
        acc[r][c] = __builtin_amdgcn_mfma_f32_16x16x32_f16(af[r], bfr[c], acc[r][c], 0, 0, 0);
    __syncthreads();
  }
#pragma unroll
  for (int r = 0; r < 4; ++r)
#pragma unroll
    for (int c = 0; c < 4; ++c)
#pragma unroll
      for (int g = 0; g < 4; ++g)
        acc[r][c][g] = __expf(fminf(acc[r][c][g], 8.f)) * 0.015625f;
#pragma unroll
  for (int r = 0; r < 4; ++r)
#pragma unroll
    for (int g = 0; g < 4; ++g) {
      float part = acc[r][0][g] + acc[r][1][g] + acc[r][2][g] + acc[r][3][g];
      part += __shfl_xor(part, 1);
      part += __shfl_xor(part, 2);
      part += __shfl_xor(part, 4);
      part += __shfl_xor(part, 8);
      if (m == 0)
        unsafeAtomicAdd(&rs[i0 + wr * 64 + r * 16 + q * 4 + g], part);
    }
#pragma unroll
  for (int r = 0; r < 4; ++r)
#pragma unroll
    for (int c = 0; c < 4; ++c)
#pragma unroll
      for (int g = 0; g < 4; ++g)
        Ts[(wr * 64 + r * 16 + q * 4 + g) * 136 + wc * 64 + c * 16 + m] =
            (_Float16)acc[r][c][g];
  __syncthreads();
#pragma unroll
  for (int it = 0; it < 8; ++it) {
    int cch = it * 4 + wave;
    int ci = cch >> 2, ck = cch & 3;
    int il = ci * 16 + (lane & 15);
    int jl = ck * 32 + (lane >> 4) * 8;
    h8 v = *(const h8*)&Ts[il * 136 + jl];
    *(h8*)&E[((bx * 8 + ci) * 256 + by * 4 + ck) * 512 + lane * 8] = v;
  }
}

// ---------- zero helpers ----------
__global__ __launch_bounds__(256) void zero_rs_kernel(float* __restrict__ rs) {
  rs[blockIdx.x * 256 + threadIdx.x] = 0.f;
}
__global__ __launch_bounds__(256) void zero_acc_kernel(float* __restrict__ a,
                                                       float* __restrict__ b) {
  size_t i = ((size_t)blockIdx.x * 256 + threadIdx.x) * 4;
  float4 z = {0.f, 0.f, 0.f, 0.f};
  *(float4*)(a + i) = z;
  *(float4*)(b + i) = z;
}

// ---------- K4: fused split-K  otm += (E@v^T)/rs, otv += (E^2@v_var^T)/rs^2 ----------
// R10: bigger wave tile for LDS-intensity. BM=128, BN=128, BK=32, 4 waves each
// computing 64x64 per GEMM (a[4] x b[4] -> 32 MFMA per 12 frag-reads = 1.67x
// the flop/LDS-byte of the 32x64 tile). Single-buffered loop (2-phase regressed
// in R9: LDS port, not latency, is the binding constraint). Split-K 4 ->
// grid (64,2,4) = 512 blocks = exactly 2 blocks/CU (capped by acc registers).
__global__ __launch_bounds__(256, 2) void av_fused(const _Float16* __restrict__ E,
                                                   const _Float16* __restrict__ vT,
                                                   const _Float16* __restrict__ vvT,
                                                   const float* __restrict__ rs,
                                                   float* __restrict__ otm,
                                                   float* __restrict__ otv) {
  __shared__ __align__(16) _Float16 As[8 * 512];    // 8 KB: 8 row-tiles (16r x 32k) of E
  __shared__ __align__(16) _Float16 B1s[8 * 512];   // 8 KB: 8 col-tiles of vT
  __shared__ __align__(16) _Float16 B2s[8 * 512];   // 8 KB: 8 col-tiles of vvT
  const int t = threadIdx.x;
  const int lane = t & 63, wave = t >> 6;
  const int wr = wave >> 1, wc = wave & 1;
  const int q = lane >> 4, m = lane & 15;
  const size_t bx = blockIdx.x, by = blockIdx.y;
  const int kt0 = blockIdx.z * 64;  // 256 k-tiles / split-K 4
  // staging: 24 wave-loads per iter, 6 per wave (2 As + 2 B1s + 2 B2s).
  const int c0 = wave * 2, c1 = wave * 2 + 1;
  size_t aoff0 = ((bx * 8 + (size_t)c0) * 256 + (size_t)kt0) * 512 + lane * 8;
  size_t aoff1 = ((bx * 8 + (size_t)c1) * 256 + (size_t)kt0) * 512 + lane * 8;
  size_t boff0 = ((by * 8 + (size_t)c0) * 256 + (size_t)kt0) * 512 + lane * 8;
  size_t boff1 = ((by * 8 + (size_t)c1) * 256 + (size_t)kt0) * 512 + lane * 8;
  floatx4 accm[4][4] = {}, accv[4][4] = {};
  for (int kk = 0; kk < 64; ++kk) {
    async_ld16(&E[aoff0],   &As[c0 * 512 + lane * 8]);
    async_ld16(&E[aoff1],   &As[c1 * 512 + lane * 8]);
    async_ld16(&vT[boff0],  &B1s[c0 * 512 + lane * 8]);
    async_ld16(&vT[boff1],  &B1s[c1 * 512 + lane * 8]);
    async_ld16(&vvT[boff0], &B2s[c0 * 512 + lane * 8]);
    async_ld16(&vvT[boff1], &B2s[c1 * 512 + lane * 8]);
    __syncthreads();
    h8 a[4], a2[4], b1[4], b2[4];
#pragma unroll
    for (int r = 0; r < 4; ++r) {
      a[r] = *(const h8*)&As[(wr * 4 + r) * 512 + lane * 8];
      a2[r] = a[r] * a[r];  // v_pk_mul_f16
    }
#pragma unroll
    for (int c = 0; c < 4; ++c) {
      b1[c] = *(const h8*)&B1s[(wc * 4 + c) * 512 + lane * 8];
      b2[c] = *(const h8*)&B2s[(wc * 4 + c) * 512 + lane * 8];
    }
#pragma unroll
    for (int r = 0; r < 4; ++r)
#pragma unroll
      for (int c = 0; c < 4; ++c) {
        accm[r][c] = __builtin_amdgcn_mfma_f32_16x16x32_f16(a[r], b1[c], accm[r][c], 0, 0, 0);
        accv[r][c] = __builtin_amdgcn_mfma_f32_16x16x32_f16(a2[r], b2[c], accv[r][c], 0, 0, 0);
      }
    __syncthreads();
    aoff0 += 512; aoff1 += 512; boff0 += 512; boff1 += 512;
  }
  // epilogue: normalize by rs (commutes with split-K sum), atomic accumulate
#pragma unroll
  for (int r = 0; r < 4; ++r)
#pragma unroll
    for (int g = 0; g < 4; ++g) {
      size_t row = bx * 128 + wr * 64 + r * 16 + q * 4 + g;
      float inv = 1.f / rs[row];
      float inv2 = inv * inv;
#pragma unroll
      for (int c = 0; c < 4; ++c) {
        size_t col = by * 128 + wc * 64 + c * 16 + m;
        unsafeAtomicAdd(&otm[row * 256 + col], accm[r][c][g] * inv);
        unsafeAtomicAdd(&otv[row * 256 + col], accv[r][c][g] * inv2);
      }
    }
}

// ---------- K5: out_mean(fp32) = otm @ Wo^T + bo.  BM=64, BN=128, grid (128,2) ----------
__global__ __launch_bounds__(256) void final_kernel(const float* __restrict__ ot,
                                                    const void* Wo, const void* bo,
                                                    const void* xdet,
                                                    float* __restrict__ Cm) {
  __shared__ __align__(16) _Float16 As[64 * 32];    // 4 KB
  __shared__ __align__(16) _Float16 Bs[128 * 32];   // 8 KB
  int isbf = detect_bf16(xdet);
  const int t = threadIdx.x;
  const int lane = t & 63, wave = t >> 6;
  const int wr = wave >> 1, wc = wave & 1;
  const int q = lane >> 4, m = lane & 15;
  const size_t i0 = (size_t)blockIdx.x * 64, j0 = (size_t)blockIdx.y * 128;
  floatx4 acc[2][4] = {};
  for (int k0 = 0; k0 < 256; k0 += 32) {
    {
      int e = t * 8;
      int row = e >> 5, col = e & 31;
      stage8h(ot, 0, (i0 + row) * (size_t)256 + k0 + col, 1.f, &As[e]);
    }
#pragma unroll
    for (int it = 0; it < 2; ++it) {
      int e = it * 2048 + t * 8;
      int row = e >> 5, col = e & 31;
      stage8h(Wo, isbf, (j0 + row) * (size_t)256 + k0 + col, 1.f, &Bs[e]);
    }
    __syncthreads();
    h8 af[2], bfr[4];
#pragma unroll
    for (int r = 0; r < 2; ++r)
      af[r] = *(const h8*)&As[(wr * 32 + r * 16 + m) * 32 + q * 8];
#pragma unroll
    for (int c = 0; c < 4; ++c)
      bfr[c] = *(const h8*)&Bs[(wc * 64 + c * 16 + m) * 32 + q * 8];
#pragma unroll
    for (int r = 0; r < 2; ++r)
#pragma unroll
      for (int c = 0; c < 4; ++c)
        acc[r][c] = __builtin_amdgcn_mfma_f32_16x16x32_f16(af[r], bfr[c], acc[r][c], 0, 0, 0);
    __syncthreads();
  }
#pragma unroll
  for (int r = 0; r < 2; ++r)
#pragma unroll
    for (int c = 0; c < 4; ++c) {
      size_t col = j0 + wc * 64 + c * 16 + m;
      float bcol = load_elem(bo, isbf, col);
#pragma unroll
      for (int g = 0; g < 4; ++g) {
        size_t row = i0 + wr * 32 + r * 16 + q * 4 + g;
        Cm[row * 256 + col] = acc[r][c][g] + bcol;
      }
    }
}

extern "C" void kernel_launch(void* const* d_in, const int* in_sizes, int n_in,
                              void* d_out, int out_size, void* d_ws, size_t ws_size,
                              hipStream_t stream) {
  const void* x_mean = d_in[0];
  const void* x_var  = d_in[1];
  // d_in[2] edge_index, d_in[3] edge_timestamps: unused by the reference
  const void* Wq   = d_in[4];
  const void* bq   = d_in[5];
  const void* Wk   = d_in[6];
  const void* bk   = d_in[7];
  const void* Wv   = d_in[8];
  const void* bv   = d_in[9];
  const void* Wo   = d_in[10];
  const void* bo   = d_in[11];
  const void* Wvar = d_in[12];
  const void* bvar = d_in[13];
  float* out = (float*)d_out;  // [out_mean (8192*256) | out_var (8192*256)] fp32

  const size_t NE_S = 67108864;  // 8192*8192
  const size_t NE_P = 2097152;   // 8192*256
  if (ws_size < (NE_S + 5 * NE_P) * 2) return;  // ~155 MB scratch
  _Float16* w   = (_Float16*)d_ws;
  _Float16* S   = w;              // E = exp(logits)*2^-6, fragment-linear [8192x8192]
  _Float16* qb  = w + NE_S;       // q*0.125 (+bq), fragment-linear [8192x256]
  _Float16* kb  = qb + NE_P;      // k, fragment-linear [8192x256]
  _Float16* vT  = kb + NE_P;      // v^T, fragment-linear [256x8192]
  _Float16* vvT = vT + NE_P;      // v_var^T, fragment-linear [256x8192]
  float* rs     = (float*)(vvT + NE_P);  // row sums of E, fp32 [8192]
  // fp32 mean accumulator aliases qb+kb (dead after qk_exp): 8 MB exactly
  float* ot_f32 = (float*)qb;

  ProjArgs p;
  p.A[0] = x_mean; p.B[0] = Wq;     p.bias[0] = bq;   p.C[0] = qb;  p.fl_tpc[0] = 8;   p.scale[0] = 0.125f; p.bias_row[0] = 0;
  p.A[1] = x_mean; p.B[1] = Wk;     p.bias[1] = bk;   p.C[1] = kb;  p.fl_tpc[1] = 8;   p.scale[1] = 1.f;    p.bias_row[1] = 0;
  p.A[2] = Wv;     p.B[2] = x_mean; p.bias[2] = bv;   p.C[2] = vT;  p.fl_tpc[2] = 256; p.scale[2] = 1.f;    p.bias_row[2] = 1;
  p.A[3] = Wvar;   p.B[3] = x_var;  p.bias[3] = bvar; p.C[3] = vvT; p.fl_tpc[3] = 256; p.scale[3] = 1.f;    p.bias_row[3] = 1;
  p.xdet = x_mean;

  zero_rs_kernel<<<dim3(32), 256, 0, stream>>>(rs);
  proj_kernel<<<dim3(64, 2, 4), 256, 0, stream>>>(p);
  qk_exp_kernel<<<dim3(64, 64), 256, 0, stream>>>(qb, kb, S, rs);
  // zero AFTER qk_exp (ot_f32 overwrites qb/kb), BEFORE av
  zero_acc_kernel<<<dim3(2048), 256, 0, stream>>>(ot_f32, out + NE_P);
  av_fused<<<dim3(64, 2, 4), 256, 0, stream>>>(S, vT, vvT, rs, ot_f32, out + NE_P);
  final_kernel<<<dim3(128, 2), 256, 0, stream>>>(ot_f32, Wo, bo, x_mean, out);
}

// Round 4
// 301.893 us; speedup vs baseline: 1.1375x; 1.0779x over previous
//
#include <hip/hip_runtime.h>
#include <hip/hip_bf16.h>
#include <hip/hip_fp16.h>

#define DEV __device__ __forceinline__

typedef __attribute__((ext_vector_type(8))) _Float16 h8;
typedef __attribute__((ext_vector_type(4))) float floatx4;

DEV float bf2f(unsigned short b) { return __uint_as_float(((unsigned)b) << 16); }

DEV void async_ld16(const void* g, void* l) {
  __builtin_amdgcn_global_load_lds(
      (const __attribute__((address_space(1))) unsigned int*)g,
      (__attribute__((address_space(3))) unsigned int*)l, 16, 0, 0);
}

// Runtime dtype probe (safety net): 1 if float tensors are bf16-packed, 0 if fp32.
DEV int detect_bf16(const void* x_mean) {
  const unsigned* w = (const unsigned*)x_mean;
  unsigned v = w[threadIdx.x & 63];
  unsigned ex = (v >> 7) & 0xFFu;
  int vote = (ex >= 100u && ex <= 144u) ? 1 : 0;
  unsigned long long b = __ballot(vote);
  return __popcll(b) >= 48 ? 1 : 0;
}

DEV float load_elem(const void* p, int isbf, size_t i) {
  return isbf ? bf2f(((const unsigned short*)p)[i]) : ((const float*)p)[i];
}

// Load 8 consecutive elements (fp32 or bf16), scale, -> 8 fp16 into LDS.
DEV void stage8h(const void* src, int isbf, size_t idx, float scale, _Float16* dst) {
  h8 o;
  if (isbf) {
    const unsigned short* s = (const unsigned short*)src + idx;
#pragma unroll
    for (int j = 0; j < 8; ++j) o[j] = (_Float16)(bf2f(s[j]) * scale);
  } else {
    const float* f = (const float*)src + idx;
    float4 a = *(const float4*)f;
    float4 b = *(const float4*)(f + 4);
    o[0] = (_Float16)(a.x * scale); o[1] = (_Float16)(a.y * scale);
    o[2] = (_Float16)(a.z * scale); o[3] = (_Float16)(a.w * scale);
    o[4] = (_Float16)(b.x * scale); o[5] = (_Float16)(b.y * scale);
    o[6] = (_Float16)(b.z * scale); o[7] = (_Float16)(b.w * scale);
  }
  *(h8*)dst = o;
}

// ---------- K1: four input projections, 128x128 tile, K=256 ----------
// Output fp16 fragment-linear via LDS-transpose epilogue (coalesced 16B stores).
struct ProjArgs {
  const void* A[4];
  const void* B[4];
  const void* bias[4];
  _Float16* C[4];
  int fl_tpc[4];
  float scale[4];
  int bias_row[4];
  const void* xdet;
};

__global__ __launch_bounds__(256) void proj_kernel(ProjArgs p) {
  __shared__ __align__(16) char smem[34816];  // k-loop: As+Bs 16 KB; epilogue: Ts 128x136
  _Float16* As = (_Float16*)smem;
  _Float16* Bs = As + 4096;
  _Float16* Ts = (_Float16*)smem;
  int isbf = detect_bf16(p.xdet);
  int z = blockIdx.z;
  size_t i0, j0;
  if (z < 2) { i0 = (size_t)blockIdx.x * 128; j0 = (size_t)blockIdx.y * 128; }
  else       { i0 = (size_t)blockIdx.y * 128; j0 = (size_t)blockIdx.x * 128; }
  const void* A = p.A[z];
  const void* B = p.B[z];
  const void* bias = p.bias[z];
  const float scale = p.scale[z];
  const int bias_row = p.bias_row[z];
  const int tpc = p.fl_tpc[z];
  _Float16* C = p.C[z];
  const int t = threadIdx.x;
  const int lane = t & 63, wave = t >> 6;
  const int wr = wave >> 1, wc = wave & 1;
  const int q = lane >> 4, m = lane & 15;
  floatx4 acc[4][4] = {};
  for (int k0 = 0; k0 < 256; k0 += 32) {
#pragma unroll
    for (int it = 0; it < 2; ++it) {
      int e = it * 2048 + t * 8;
      int row = e >> 5, col = e & 31;
      stage8h(A, isbf, (i0 + row) * (size_t)256 + k0 + col, 1.f, &As[e]);
      stage8h(B, isbf, (j0 + row) * (size_t)256 + k0 + col, 1.f, &Bs[e]);
    }
    __syncthreads();
    h8 af[4], bfr[4];
#pragma unroll
    for (int r = 0; r < 4; ++r)
      af[r] = *(const h8*)&As[(wr * 64 + r * 16 + m) * 32 + q * 8];
#pragma unroll
    for (int c = 0; c < 4; ++c)
      bfr[c] = *(const h8*)&Bs[(wc * 64 + c * 16 + m) * 32 + q * 8];
#pragma unroll
    for (int r = 0; r < 4; ++r)
#pragma unroll
      for (int c = 0; c < 4; ++c)
        acc[r][c] = __builtin_amdgcn_mfma_f32_16x16x32_f16(af[r], bfr[c], acc[r][c], 0, 0, 0);
    __syncthreads();
  }
  // bias + scale, into LDS transpose buffer
#pragma unroll
  for (int r = 0; r < 4; ++r)
#pragma unroll
    for (int c = 0; c < 4; ++c) {
      size_t col = j0 + wc * 64 + c * 16 + m;
      float bcol = bias_row ? 0.f : load_elem(bias, isbf, col);
#pragma unroll
      for (int g = 0; g < 4; ++g) {
        size_t row = i0 + wr * 64 + r * 16 + q * 4 + g;
        float val = acc[r][c][g] + bcol;
        if (bias_row) val += load_elem(bias, isbf, row);
        Ts[(wr * 64 + r * 16 + q * 4 + g) * 136 + wc * 64 + c * 16 + m] =
            (_Float16)(val * scale);
      }
    }
  __syncthreads();
  // coalesced fragment-linear writeout: 32 tiles, 16 B/lane
  size_t ti0 = i0 >> 4, tj0 = j0 >> 5;
#pragma unroll
  for (int it = 0; it < 8; ++it) {
    int cch = it * 4 + wave;
    int ci = cch >> 2, ck = cch & 3;
    int il = ci * 16 + (lane & 15);
    int jl = ck * 32 + (lane >> 4) * 8;
    h8 v = *(const h8*)&Ts[il * 136 + jl];
    *(h8*)&C[((ti0 + ci) * (size_t)tpc + (tj0 + ck)) * 512 + lane * 8] = v;
  }
}

// ---------- zero helpers ----------
__global__ __launch_bounds__(256) void zero_rs_kernel(float* __restrict__ rs) {
  rs[blockIdx.x * 256 + threadIdx.x] = 0.f;
}
__global__ __launch_bounds__(256) void zero_acc_kernel(float* __restrict__ a,
                                                       float* __restrict__ b) {
  size_t i = ((size_t)blockIdx.x * 256 + threadIdx.x) * 4;
  float4 z = {0.f, 0.f, 0.f, 0.f};
  *(float4*)(a + i) = z;
  *(float4*)(b + i) = z;
}

// ---------- K3: flash-fused attention ----------
// Never materializes S/E in HBM. Per block: Q-tile 128 rows x 256, KV range 2048
// (16 kv-tiles of 128). S-tile -> exp -> P in LDS (PV A-fragment layout) -> PV
// accumulating in registers. Unnormalized sums (P@v, P^2@vvar, rowsum) are
// atomically accumulated; normalization by rs happens in final_kernel.
// No-max-rescale softmax (exp(min(s,8))*2^-6) => kv-split partials are additive.
// 8 waves / 512 threads; S-phase split 4q x 2kv; PV split 2q x 4d.
// LDS: Qs 64K + Ks 32K + Ps 32K = 128 KB -> 1 block/CU, 2 waves/SIMD.
__global__ __launch_bounds__(512, 2) void flash_kernel(
    const _Float16* __restrict__ qb, const _Float16* __restrict__ kb,
    const _Float16* __restrict__ vT, const _Float16* __restrict__ vvT,
    float* __restrict__ rs, float* __restrict__ otm, float* __restrict__ otv) {
  __shared__ __align__(16) _Float16 Qs[64 * 512];  // 64 KB: q 128x256, frag-linear [rt*8+kt]
  __shared__ __align__(16) _Float16 Ks[32 * 512];  // 32 KB: k chunk 128kv x 128k [kvtile*4+kt2]
  __shared__ __align__(16) _Float16 Ps[32 * 512];  // 32 KB: P 128x128, frag-linear [qt*4+kst]
  const int t = threadIdx.x;
  const int lane = t & 63, wave = t >> 6;  // 8 waves
  const int hi = lane >> 4, m = lane & 15;
  const size_t bx = blockIdx.x;  // q-block (128 rows)
  const int z = blockIdx.y;      // kv split (2048 kv each)
  const int wq = wave >> 1, wk = wave & 1;   // S-phase: 4q x 2kv
  const int wq2 = wave >> 2, wd = wave & 3;  // PV: 2q x 4d

  // stage Q once (64 tiles of 1 KB; drained by the first barrier below)
#pragma unroll
  for (int it = 0; it < 8; ++it) {
    int tile = it * 8 + wave;  // rt*8 + kt
    async_ld16(&qb[((bx * 8 + (size_t)(tile >> 3)) * 8 + (tile & 7)) * 512 + lane * 8],
               &Qs[tile * 512 + lane * 8]);
  }
  floatx4 accm[4][4] = {}, accv[4][4] = {};
  float rsum[2][4] = {};
  const size_t kvRowBase = (size_t)z * 128;  // kv row-tile base (16-row tiles)
  for (int kvt = 0; kvt < 16; ++kvt) {
    floatx4 s[2][4] = {};
    const size_t kvRow0 = kvRowBase + kvt * 8;
    // K=256 in 2 chunks of 128
#pragma unroll
    for (int ko = 0; ko < 2; ++ko) {
      // stage 32 KB: wave stages its kv-row-tile, 4 k-subtiles
#pragma unroll
      for (int it = 0; it < 4; ++it)
        async_ld16(&kb[((kvRow0 + wave) * 8 + (size_t)(ko * 4 + it)) * 512 + lane * 8],
                   &Ks[(wave * 4 + it) * 512 + lane * 8]);
      __syncthreads();
#pragma unroll
      for (int kt2 = 0; kt2 < 4; ++kt2) {
        h8 af[2], bf[4];
#pragma unroll
        for (int r = 0; r < 2; ++r)
          af[r] = *(const h8*)&Qs[((wq * 2 + r) * 8 + ko * 4 + kt2) * 512 + lane * 8];
#pragma unroll
        for (int c = 0; c < 4; ++c)
          bf[c] = *(const h8*)&Ks[((wk * 4 + c) * 4 + kt2) * 512 + lane * 8];
#pragma unroll
        for (int r = 0; r < 2; ++r)
#pragma unroll
          for (int c = 0; c < 4; ++c)
            s[r][c] = __builtin_amdgcn_mfma_f32_16x16x32_f16(af[r], bf[c], s[r][c], 0, 0, 0);
      }
      __syncthreads();
    }
    // exp + rsum + scatter P into PV A-fragment layout.
    // S acc: q = wq*32 + r*16 + hi*4 + g, kv = wk*64 + c*16 + m.
    // A-frag slot for P[q,kv]: tile (q>>4)*4 + (kv>>5); half l'*8 + (kv&7),
    // l' = (q&15) | (((kv>>3)&3) << 4).
#pragma unroll
    for (int r = 0; r < 2; ++r)
#pragma unroll
      for (int c = 0; c < 4; ++c) {
        int kst = wk * 2 + (c >> 1);
        int lp = hi * 4 + 16 * (2 * (c & 1) + (m >> 3));
        _Float16* dst = &Ps[((wq * 2 + r) * 4 + kst) * 512 + lp * 8 + (m & 7)];
#pragma unroll
        for (int g = 0; g < 4; ++g) {
          float e = __expf(fminf(s[r][c][g], 8.f)) * 0.015625f;
          rsum[r][g] += e;
          dst[g * 8] = (_Float16)e;  // l' increments by 1 per g -> +8 halfs
        }
      }
    __syncthreads();
    // PV: accm += P @ vT-frags, accv += P^2 @ vvT-frags (B direct global->reg)
    const size_t kvT0 = (size_t)z * 64 + kvt * 4;  // kv col-tile base (32 each)
#pragma unroll
    for (int ks = 0; ks < 4; ++ks) {
      h8 a[4], a2[4], b1[4], b2[4];
#pragma unroll
      for (int c = 0; c < 4; ++c) {
        size_t bo_ = ((size_t)(wd * 4 + c) * 256 + kvT0 + ks) * 512 + lane * 8;
        b1[c] = *(const h8*)&vT[bo_];
        b2[c] = *(const h8*)&vvT[bo_];
      }
#pragma unroll
      for (int r = 0; r < 4; ++r) {
        a[r] = *(const h8*)&Ps[((wq2 * 4 + r) * 4 + ks) * 512 + lane * 8];
        a2[r] = a[r] * a[r];  // v_pk_mul_f16
      }
#pragma unroll
      for (int r = 0; r < 4; ++r)
#pragma unroll
        for (int c = 0; c < 4; ++c) {
          accm[r][c] = __builtin_amdgcn_mfma_f32_16x16x32_f16(a[r], b1[c], accm[r][c], 0, 0, 0);
          accv[r][c] = __builtin_amdgcn_mfma_f32_16x16x32_f16(a2[r], b2[c], accv[r][c], 0, 0, 0);
        }
    }
    // no barrier needed: next tile's Ks stage/Ps writes are ordered by its own
    // barriers; all PV ds_reads complete before any wave passes those.
  }
  // rowsum reduce (over m) + one atomic per q-row per wave
#pragma unroll
  for (int r = 0; r < 2; ++r)
#pragma unroll
    for (int g = 0; g < 4; ++g) {
      float part = rsum[r][g];
      part += __shfl_xor(part, 1);
      part += __shfl_xor(part, 2);
      part += __shfl_xor(part, 4);
      part += __shfl_xor(part, 8);
      if (m == 0)
        unsafeAtomicAdd(&rs[bx * 128 + wq * 32 + r * 16 + hi * 4 + g], part);
    }
  // unnormalized partial outputs
#pragma unroll
  for (int r = 0; r < 4; ++r)
#pragma unroll
    for (int g = 0; g < 4; ++g) {
      size_t row = bx * 128 + wq2 * 64 + r * 16 + hi * 4 + g;
#pragma unroll
      for (int c = 0; c < 4; ++c) {
        size_t col = wd * 64 + c * 16 + m;
        unsafeAtomicAdd(&otm[row * 256 + col], accm[r][c][g]);
        unsafeAtomicAdd(&otv[row * 256 + col], accv[r][c][g]);
      }
    }
}

// ---------- K5: out_mean = (otm @ Wo^T)/rs + bo; also out_var *= 1/rs^2 ----------
__global__ __launch_bounds__(256) void final_kernel(const float* __restrict__ ot,
                                                    const void* Wo, const void* bo,
                                                    const void* xdet,
                                                    const float* __restrict__ rs,
                                                    float* __restrict__ Cm,
                                                    float* __restrict__ otv) {
  __shared__ __align__(16) _Float16 As[64 * 32];    // 4 KB
  __shared__ __align__(16) _Float16 Bs[128 * 32];   // 8 KB
  int isbf = detect_bf16(xdet);
  const int t = threadIdx.x;
  const int lane = t & 63, wave = t >> 6;
  const int wr = wave >> 1, wc = wave & 1;
  const int q = lane >> 4, m = lane & 15;
  const size_t i0 = (size_t)blockIdx.x * 64, j0 = (size_t)blockIdx.y * 128;
  floatx4 acc[2][4] = {};
  for (int k0 = 0; k0 < 256; k0 += 32) {
    {
      int e = t * 8;
      int row = e >> 5, col = e & 31;
      stage8h(ot, 0, (i0 + row) * (size_t)256 + k0 + col, 1.f, &As[e]);
    }
#pragma unroll
    for (int it = 0; it < 2; ++it) {
      int e = it * 2048 + t * 8;
      int row = e >> 5, col = e & 31;
      stage8h(Wo, isbf, (j0 + row) * (size_t)256 + k0 + col, 1.f, &Bs[e]);
    }
    __syncthreads();
    h8 af[2], bfr[4];
#pragma unroll
    for (int r = 0; r < 2; ++r)
      af[r] = *(const h8*)&As[(wr * 32 + r * 16 + m) * 32 + q * 8];
#pragma unroll
    for (int c = 0; c < 4; ++c)
      bfr[c] = *(const h8*)&Bs[(wc * 64 + c * 16 + m) * 32 + q * 8];
#pragma unroll
    for (int r = 0; r < 2; ++r)
#pragma unroll
      for (int c = 0; c < 4; ++c)
        acc[r][c] = __builtin_amdgcn_mfma_f32_16x16x32_f16(af[r], bfr[c], acc[r][c], 0, 0, 0);
    __syncthreads();
  }
#pragma unroll
  for (int r = 0; r < 2; ++r)
#pragma unroll
    for (int g = 0; g < 4; ++g) {
      size_t row = i0 + wr * 32 + r * 16 + q * 4 + g;
      float inv = 1.f / rs[row];
#pragma unroll
      for (int c = 0; c < 4; ++c) {
        size_t col = j0 + wc * 64 + c * 16 + m;
        float bcol = load_elem(bo, isbf, col);
        Cm[row * 256 + col] = acc[r][c][g] * inv + bcol;
      }
    }
  // normalize out_var slice in-place: rows [i0,i0+64), cols [j0,j0+128)
#pragma unroll
  for (int it = 0; it < 8; ++it) {
    int e = it * 256 + t;          // 2048 float4 groups per block
    int row = e >> 5, cg = e & 31; // 64 rows x 32 col-groups of 4
    size_t rrow = i0 + row;
    float inv = 1.f / rs[rrow];
    float inv2 = inv * inv;
    float4* pp = (float4*)&otv[rrow * 256 + j0 + cg * 4];
    float4 v = *pp;
    v.x *= inv2; v.y *= inv2; v.z *= inv2; v.w *= inv2;
    *pp = v;
  }
}

extern "C" void kernel_launch(void* const* d_in, const int* in_sizes, int n_in,
                              void* d_out, int out_size, void* d_ws, size_t ws_size,
                              hipStream_t stream) {
  const void* x_mean = d_in[0];
  const void* x_var  = d_in[1];
  // d_in[2] edge_index, d_in[3] edge_timestamps: unused by the reference
  const void* Wq   = d_in[4];
  const void* bq   = d_in[5];
  const void* Wk   = d_in[6];
  const void* bk   = d_in[7];
  const void* Wv   = d_in[8];
  const void* bv   = d_in[9];
  const void* Wo   = d_in[10];
  const void* bo   = d_in[11];
  const void* Wvar = d_in[12];
  const void* bvar = d_in[13];
  float* out = (float*)d_out;  // [out_mean (8192*256) | out_var (8192*256)] fp32

  const size_t NE_S = 67108864;  // 8192*8192 (unused now; kept for ws check)
  const size_t NE_P = 2097152;   // 8192*256
  if (ws_size < (NE_S + 5 * NE_P) * 2) return;
  _Float16* w   = (_Float16*)d_ws;
  _Float16* qb  = w;              // q*0.125 (+bq), fragment-linear [8192x256]
  _Float16* kb  = qb + NE_P;      // k, fragment-linear [8192x256]
  _Float16* vT  = kb + NE_P;      // v^T, fragment-linear [256x8192]
  _Float16* vvT = vT + NE_P;      // v_var^T, fragment-linear [256x8192]
  float* rs     = (float*)(vvT + NE_P);  // row sums of exp, fp32 [8192]
  float* ot_f32 = rs + 8192;             // unnormalized P@v accumulator, fp32 [8192x256]

  ProjArgs p;
  p.A[0] = x_mean; p.B[0] = Wq;     p.bias[0] = bq;   p.C[0] = qb;  p.fl_tpc[0] = 8;   p.scale[0] = 0.125f; p.bias_row[0] = 0;
  p.A[1] = x_mean; p.B[1] = Wk;     p.bias[1] = bk;   p.C[1] = kb;  p.fl_tpc[1] = 8;   p.scale[1] = 1.f;    p.bias_row[1] = 0;
  p.A[2] = Wv;     p.B[2] = x_mean; p.bias[2] = bv;   p.C[2] = vT;  p.fl_tpc[2] = 256; p.scale[2] = 1.f;    p.bias_row[2] = 1;
  p.A[3] = Wvar;   p.B[3] = x_var;  p.bias[3] = bvar; p.C[3] = vvT; p.fl_tpc[3] = 256; p.scale[3] = 1.f;    p.bias_row[3] = 1;
  p.xdet = x_mean;

  zero_rs_kernel<<<dim3(32), 256, 0, stream>>>(rs);
  zero_acc_kernel<<<dim3(2048), 256, 0, stream>>>(ot_f32, out + NE_P);
  proj_kernel<<<dim3(64, 2, 4), 256, 0, stream>>>(p);
  flash_kernel<<<dim3(64, 4), 512, 0, stream>>>(qb, kb, vT, vvT, rs, ot_f32, out + NE_P);
  final_kernel<<<dim3(128, 2), 256, 0, stream>>>(ot_f32, Wo, bo, x_mean, rs, out, out + NE_P);
}